// Round 10
// baseline (215.424 us; speedup 1.0000x reference)
//
#include <hip/hip_runtime.h>
#include <math.h>

typedef _Float16 f16;
typedef f16  f16x2 __attribute__((ext_vector_type(2)));
typedef f16  f16x4 __attribute__((ext_vector_type(4)));
typedef f16  f16x8 __attribute__((ext_vector_type(8)));
typedef float f32x4 __attribute__((ext_vector_type(4)));

#define F4(p)  (*(float4*)(p))
#define CF4(p) (*(const float4*)(p))

namespace {
constexpr int LL = 4096;   // sequence
constexpr int HH = 64;     // channels
constexpr int NCH = 16;    // split-K l-chunks (256 l each)

__device__ __forceinline__ float gelu_fast(float x) {
    // 0.5x(1+tanh(i)) == x*sigmoid(2i); exp-neg form is NaN-free at +/-inf
    float inner = 0.7978845608028654f * (x + 0.044715f * x * x * x);
    float e = __expf(-2.0f * inner);
    return x / (1.0f + e);
}

__device__ __forceinline__ f32x4 mfma16(f16x8 a, f16x8 b, f32x4 c) {
    return __builtin_amdgcn_mfma_f32_16x16x32_f16(a, b, c, 0, 0, 0);
}
} // namespace

// ---------------------------------------------------------------------------
// k_init: fused lift [0,512) + twiddle [512,1536) + wr/wi fp16 cvt [1536,2560)
//   Tdt[m2][l]:  cos(2pi m l/L), -sin                (DFT weights, f16)
//   Ttr[l][m2]: (m==0?1:2cos)/L, (m==0?0:-2sin)/L    (irfft weights, f16)
// Both tables written COALESCED (lane runs along the contiguous dim).
// ---------------------------------------------------------------------------
__global__ __launch_bounds__(256) void k_init(const float* __restrict__ u,
                                              const float* __restrict__ z,
                                              const float* __restrict__ wl,
                                              const float* __restrict__ bl,
                                              const float* __restrict__ wsk,
                                              const float* __restrict__ wr,
                                              const float* __restrict__ wi,
                                              f16* __restrict__ Tdt,
                                              f16* __restrict__ Ttr,
                                              f16* __restrict__ wskh,
                                              f16* __restrict__ wrh,
                                              f16* __restrict__ wih,
                                              f16* __restrict__ XT0) {
    const int bid = blockIdx.x;
    const int t = threadIdx.x;
    if (bid < 512) {
        // ---- lift: XT0[b][l][h], register-tiled 8h x 8l per thread
        const int b = bid >> 4;
        const int l0 = (bid & 15) * 256;
        constexpr int IP = 260;
        __shared__ float in_s[16 * IP];
        __shared__ float wsh[64 * 16];
        __shared__ float bsh[64];
        for (int i = t; i < 1024; i += 256) wsh[i] = wl[i];
        if (t < 64) bsh[t] = bl[t];
#pragma unroll
        for (int q = 0; q < 2; ++q) {
            int f = t + q * 256;
            int l = f >> 1, cq = (f & 1) * 4;
            float4 v = CF4(u + ((size_t)b * LL + l0 + l) * 8 + cq);
            in_s[(cq + 0) * IP + l] = v.x;
            in_s[(cq + 1) * IP + l] = v.y;
            in_s[(cq + 2) * IP + l] = v.z;
            in_s[(cq + 3) * IP + l] = v.w;
        }
        for (int f = t; f < 8 * 256; f += 256) {
            int c = f >> 8, l = f & 255;
            in_s[(8 + c) * IP + l] = z[b * 8 + c];
        }
        __syncthreads();
        const int hg = t >> 5, lsub = t & 31;
        float acc[8][8] = {};
        for (int c = 0; c < 16; ++c) {
            float wv[8], inv[8];
#pragma unroll
            for (int i = 0; i < 8; ++i) wv[i] = wsh[(hg * 8 + i) * 16 + c];
#pragma unroll
            for (int j = 0; j < 8; ++j) inv[j] = in_s[c * IP + lsub + 32 * j];
#pragma unroll
            for (int i = 0; i < 8; ++i)
#pragma unroll
                for (int j = 0; j < 8; ++j) acc[i][j] += wv[i] * inv[j];
        }
#pragma unroll
        for (int j = 0; j < 8; ++j) {
            __attribute__((aligned(16))) f16 hv[8];
#pragma unroll
            for (int i = 0; i < 8; ++i) hv[i] = (f16)(acc[i][j] + bsh[hg * 8 + i]);
            int l = l0 + lsub + 32 * j;
            F4(XT0 + ((size_t)b * LL + l) * HH + hg * 8) = CF4(hv);
        }
    } else if (bid < 1536) {
        // ---- twiddle (both orientations coalesced)
        const int tb = bid - 512;
        const float w0 = 6.283185307179586f / 4096.0f;
        {   // Tdt: lane runs along l
            int m = tb >> 4;
            int l = ((tb & 15) << 8) + t;
            float s, c;
            sincosf((float)((l * m) & 4095) * w0, &s, &c);
            Tdt[(size_t)(2 * m) * LL + l]     = (f16)c;
            Tdt[(size_t)(2 * m + 1) * LL + l] = (f16)(-s);
        }
        {   // Ttr: lane runs along m2 (4B per lane)
            int l = tb * 4 + (t >> 6);
            int m = t & 63;
            float s, c;
            sincosf((float)((l * m) & 4095) * w0, &s, &c);
            const float sc = 1.0f / 4096.0f;
            f16x2 pv;
            pv.x = (f16)((m == 0) ? sc : 2.0f * sc * c);
            pv.y = (f16)((m == 0) ? 0.0f : -2.0f * sc * s);
            *(f16x2*)(Ttr + (size_t)l * 128 + 2 * m) = pv;
        }
        if (tb < 64) {
            int idx = tb * 256 + t;
            wskh[idx] = (f16)wsk[idx];
        }
    } else {
        // ---- wr/wi -> f16 (4 elements each per thread)
        const int cb = bid - 1536;
        size_t base = (size_t)cb * 1024 + t * 4;
        float4 vr = CF4(wr + base);
        float4 vi = CF4(wi + base);
        f16x4 hr, hi;
        hr.x = (f16)vr.x; hr.y = (f16)vr.y; hr.z = (f16)vr.z; hr.w = (f16)vr.w;
        hi.x = (f16)vi.x; hi.y = (f16)vi.y; hi.z = (f16)vi.z; hi.w = (f16)vi.w;
        *(f16x4*)(wrh + base) = hr;
        *(f16x4*)(wih + base) = hi;
    }
}

// ---------------------------------------------------------------------------
// Partial DFT (LAYER 0 ONLY), fp16 MFMA, 16-chunk split (K=256 each):
//   Y[ch][(b,h)][m2] = sum_{l in 256-chunk} XT[b][l][h] * Tdt[m2][l]   (f16 out)
// grid (32 = ch*2+hhalf, 32 b), block 256 (4 waves). Tile 32 h x 128 m2.
// Register-prefetch pipeline: next chunk's global loads issue BEFORE the
// current chunk's MFMA; the ds_write (and its vmcnt drain) lands AFTER the
// MFMA cluster. Barrier count unchanged; LDS unchanged (4 blocks/CU kept).
// ---------------------------------------------------------------------------
__global__ __launch_bounds__(256) void k_dft(const f16* __restrict__ XT,
                                             const f16* __restrict__ Tdt,
                                             f16* __restrict__ Y) {
    __shared__ f16 Asl[32 * 72];    // [h][l-chunk] pitch 72
    __shared__ f16 Bsl[128 * 72];   // [m2][l-chunk] pitch 72
    const int t = threadIdx.x;
    const int ch = blockIdx.x >> 1, h0 = (blockIdx.x & 1) * 32, b = blockIdx.y;
    const int lane = t & 63, wid = t >> 6;
    const int mh = (wid & 1) * 16, n0 = (wid >> 1) * 64;
    const int fm = lane & 15, fq = lane >> 4;
    const int seg = t >> 6;
    const int br = t >> 3, bcol = (t & 7) * 8;
    f32x4 acc[4] = {};
    f16x8 rA;
    float4 rb[4];
    auto ldAB = [&](int k0) {
        const int l0 = ch * 256 + k0;
        rA = *(const f16x8*)(XT + ((size_t)b * LL + l0 + lane) * HH + h0 + seg * 8);
#pragma unroll
        for (int p = 0; p < 4; ++p)
            rb[p] = CF4(Tdt + (size_t)(br + p * 32) * LL + l0 + bcol);
    };
    auto wrAB = [&]() {
#pragma unroll
        for (int i = 0; i < 8; ++i) Asl[(seg * 8 + i) * 72 + lane] = rA[i];
#pragma unroll
        for (int p = 0; p < 4; ++p)
            F4(&Bsl[(br + p * 32) * 72 + bcol]) = rb[p];
    };
    ldAB(0);
    wrAB();
    for (int k0 = 0; k0 < 256; k0 += 64) {
        if (k0 < 192) ldAB(k0 + 64);    // prefetch next chunk under this MFMA
        __syncthreads();                // current chunk's writes visible
#pragma unroll
        for (int ks = 0; ks < 64; ks += 32) {
            f16x8 a = *(const f16x8*)&Asl[(mh + fm) * 72 + ks + fq * 8];
#pragma unroll
            for (int j = 0; j < 4; ++j) {
                f16x8 bj = *(const f16x8*)&Bsl[(n0 + j * 16 + fm) * 72 + ks + fq * 8];
                acc[j] = mfma16(a, bj, acc[j]);
            }
        }
        __syncthreads();                // frag reads done
        if (k0 < 192) wrAB();           // drain lands here, after the MFMAs
    }
    f16* yp = Y + ((size_t)ch * 2048 + b * HH + h0) * 128;
#pragma unroll
    for (int j = 0; j < 4; ++j)
#pragma unroll
        for (int r = 0; r < 4; ++r)
            yp[(size_t)(mh + fq * 4 + r) * 128 + n0 + j * 16 + fm] = (f16)acc[j][r];
}

// ---------------------------------------------------------------------------
// Spectral mix + split-K reduce (16 chunks). grid (32 b, 16 og).
// f16 Y and weights, fp32 math, f16 out.
// ---------------------------------------------------------------------------
__global__ __launch_bounds__(256) void k_spec(const f16* __restrict__ Y,
                                              const f16* __restrict__ wrh,
                                              const f16* __restrict__ wih,
                                              f16* __restrict__ Ofh, int layer) {
    __shared__ float xsh[64 * 128];
    const int t = threadIdx.x;
    const int b = blockIdx.x;
    const int og = blockIdx.y;
    {   // stage Xf[b] = sum_ch Y[ch][b]  (ascending ch, fp32 accum)
#pragma unroll
        for (int i = 0; i < 4; ++i) {
            int g = t + i * 256;            // f16x8 group, 1024 total
            float s[8] = {};
#pragma unroll
            for (int c = 0; c < NCH; ++c) {
                f16x8 v = *(const f16x8*)(Y + ((size_t)c * 2048 + b * HH) * 128 + g * 8);
#pragma unroll
                for (int e = 0; e < 8; ++e) s[e] += (float)v[e];
            }
#pragma unroll
            for (int e = 0; e < 8; ++e) xsh[g * 8 + e] = s[e];
        }
    }
    __syncthreads();
    const int m = t & 63, osub = t >> 6;
    const int o = og * 4 + osub;
    const f16* wrp = wrh + ((size_t)layer * HH + o) * HH * 64 + m;
    const f16* wip = wih + ((size_t)layer * HH + o) * HH * 64 + m;
    float are = 0.0f, aim = 0.0f;
    const float2* xs2 = (const float2*)xsh;
#pragma unroll 8
    for (int i = 0; i < 64; ++i) {
        float2 xv = xs2[i * 64 + m];
        float wrv = (float)wrp[(size_t)i * 64];
        float wiv = (float)wip[(size_t)i * 64];
        are += xv.x * wrv - xv.y * wiv;
        aim += xv.x * wiv + xv.y * wrv;
    }
    f16x2 ov; ov.x = (f16)are; ov.y = (f16)aim;
    *(f16x2*)(Ofh + ((size_t)b * HH + o) * 128 + 2 * m) = ov;
}

// ---------------------------------------------------------------------------
// FUSED recon(layer) + partial-DFT(layer+1), layers 0..2.
// grid (16 lc, 32 b) = 512 blocks, block 512 (8 waves), 2 blocks/CU.
// DOUBLE-BUFFERED Bsl (B0/B1, 80.1 KB total): each phase issues next chunk's
// global loads, runs MFMA on buf[p], then ds_writes buf[p^1] — the barrier's
// vmcnt(0) drain lands AFTER a full MFMA cluster instead of immediately after
// issue. Barriers per block ~15 (was ~25). Math/order identical to r3.
// ---------------------------------------------------------------------------
__global__ __launch_bounds__(512, 4) void k_fused(const f16* __restrict__ Ofh,
                                                  const f16* __restrict__ XTold,
                                                  const f16* __restrict__ Ttr,
                                                  const f16* __restrict__ wskh,
                                                  const float* __restrict__ bsk,
                                                  const f16* __restrict__ Tdt,
                                                  f16* __restrict__ XTn,
                                                  f16* __restrict__ Y,
                                                  int layer) {
    __shared__ __align__(16) char smem[80128];
    f16* Asl = (f16*)smem;                 // [64][200] = 25600
    f16* XA  = (f16*)(smem + 25600);       // [64][136] = 17408 (ends 43008)
    f16* B0  = (f16*)(smem + 43008);       // [128][72] = 18432 (ends 61440)
    f16* B1  = (f16*)(smem + 61440);       // [128][72] = 18432 (ends 79872)
    float* bss = (float*)(smem + 79872);   // 64*4 = 256 (ends 80128)
    const int t = threadIdx.x;
    const int lc = blockIdx.x, b = blockIdx.y;
    const int lane = t & 63, wid = t >> 6;
    const int ow = (wid & 1) * 32;        // o rows (recon) / h rows (dft)
    const int n0 = (wid >> 1) * 32;       // l cols (recon) / m2 cols (dft)
    const int fm = lane & 15, fq = lane >> 4;
    const int br = t >> 3, bcol = (t & 7) * 8;   // B-stage rows br, br+64 @ col bcol

    float4 rB0, rB1;
    auto ldR = [&](int ls, int c) {       // recon B rows: Ttr (c<2) or XTold (c==2)
        const int l0g = lc * 256 + ls * 128;
        if (c < 2) {
            rB0 = CF4(Ttr + (size_t)(l0g + br) * 128 + c * 64 + bcol);
            rB1 = CF4(Ttr + (size_t)(l0g + br + 64) * 128 + c * 64 + bcol);
        } else {
            rB0 = CF4(XTold + ((size_t)b * LL + l0g + br) * HH + bcol);
            rB1 = CF4(XTold + ((size_t)b * LL + l0g + br + 64) * HH + bcol);
        }
    };
    auto ldD = [&](int ls, int c) {       // dft B rows: Tdt[m2][l-chunk]
        const int l0 = lc * 256 + ls * 128 + c * 64;
        rB0 = CF4(Tdt + (size_t)br * LL + l0 + bcol);
        rB1 = CF4(Tdt + (size_t)(br + 64) * LL + l0 + bcol);
    };
    auto wrB = [&](f16* buf) {
        F4(&buf[br * 72 + bcol]) = rB0;
        F4(&buf[(br + 64) * 72 + bcol]) = rB1;
    };
    f32x4 acc[2][2];
    f32x4 Yac[2][2] = {};
    auto reconMM = [&](const f16* buf, int k0) {
#pragma unroll
        for (int ks = 0; ks < 64; ks += 32) {
            f16x8 a0 = *(const f16x8*)&Asl[(ow + fm) * 200 + k0 + ks + fq * 8];
            f16x8 a1 = *(const f16x8*)&Asl[(ow + 16 + fm) * 200 + k0 + ks + fq * 8];
#pragma unroll
            for (int j = 0; j < 2; ++j) {
                f16x8 bj = *(const f16x8*)&buf[(n0 + j * 16 + fm) * 72 + ks + fq * 8];
                acc[0][j] = mfma16(a0, bj, acc[0][j]);
                acc[1][j] = mfma16(a1, bj, acc[1][j]);
            }
        }
    };
    auto dftMM = [&](const f16* buf, int c) {
#pragma unroll
        for (int ks = 0; ks < 64; ks += 32) {
            f16x8 a0 = *(const f16x8*)&XA[(ow + fm) * 136 + c * 64 + ks + fq * 8];
            f16x8 a1 = *(const f16x8*)&XA[(ow + 16 + fm) * 136 + c * 64 + ks + fq * 8];
#pragma unroll
            for (int j = 0; j < 2; ++j) {
                f16x8 bj = *(const f16x8*)&buf[(n0 + j * 16 + fm) * 72 + ks + fq * 8];
                Yac[0][j] = mfma16(a0, bj, Yac[0][j]);
                Yac[1][j] = mfma16(a1, bj, Yac[1][j]);
            }
        }
    };

    {   // prologue: stage Asl = [Of[b] | wskh[layer]], bss, and R0(ls=0) -> B0
        int seg = t & 15, row = t >> 4;   // row 0..31
#pragma unroll
        for (int p = 0; p < 2; ++p) {
            int r = row + p * 32;
            F4(&Asl[r * 200 + seg * 8]) = CF4(Ofh + ((size_t)(b * HH + r)) * 128 + seg * 8);
        }
        F4(&Asl[br * 200 + 128 + bcol]) =
            CF4(wskh + ((size_t)(layer * HH + br)) * HH + bcol);
        if (t < 64) bss[t] = bsk[layer * HH + t];
        ldR(0, 0);
        wrB(B0);
    }
    __syncthreads();

#pragma unroll
    for (int ls = 0; ls < 2; ++ls) {
        const int l0g = lc * 256 + ls * 128;
        f16* bA = (ls == 0) ? B0 : B1;    // buffer holding this ls's R0
        f16* bB = (ls == 0) ? B1 : B0;
#pragma unroll
        for (int i = 0; i < 2; ++i)
#pragma unroll
            for (int j = 0; j < 2; ++j) acc[i][j] = (f32x4){0.f, 0.f, 0.f, 0.f};
        // P0: R0 MFMA on bA; prefetch R1 -> bB
        ldR(ls, 1);
        reconMM(bA, 0);
        wrB(bB);
        __syncthreads();
        // P1: R1 MFMA on bB; prefetch R2 -> bA
        ldR(ls, 2);
        reconMM(bB, 64);
        wrB(bA);
        __syncthreads();
        // P2: R2 MFMA on bA; prefetch D0 -> bB
        ldD(ls, 0);
        reconMM(bA, 128);
        wrB(bB);
        __syncthreads();
        // P3: epilogue — bias+gelu; write XA[o][l] (dft A) + bA[l][o] (XT stage)
#pragma unroll
        for (int i = 0; i < 2; ++i)
#pragma unroll
            for (int r = 0; r < 4; ++r) {
                int row = ow + i * 16 + fq * 4 + r;
                float bias = bss[row];
#pragma unroll
                for (int j = 0; j < 2; ++j) {
                    int lcn = n0 + j * 16 + fm;
                    f16 hv = (f16)gelu_fast(acc[i][j][r] + bias);
                    XA[row * 136 + lcn] = hv;
                    bA[lcn * 72 + row] = hv;
                }
            }
        __syncthreads();
        // P4: XTn write from bA ∥ D0 MFMA on bB ∥ issue D1 loads
        if (layer < 2) {
            F4(XTn + ((size_t)b * LL + l0g + br) * HH + bcol) = CF4(&bA[br * 72 + bcol]);
            F4(XTn + ((size_t)b * LL + l0g + br + 64) * HH + bcol) =
                CF4(&bA[(br + 64) * 72 + bcol]);
        } else if (lc == NCH - 1 && ls == 1) {
            // layer 2: only l = L-1 is ever consumed (k_final skip term)
            if (t < 64) XTn[((size_t)b * LL + (LL - 1)) * HH + t] = bA[127 * 72 + t];
        }
        ldD(ls, 1);
        dftMM(bB, 0);
        __syncthreads();
        // P5: D1 -> bA (XTn-stage reads done); prefetch next ls's R0
        wrB(bA);
        if (ls == 0) ldR(1, 0);
        __syncthreads();
        // P6: D1 MFMA on bA; stage next R0 -> bB
        dftMM(bA, 1);
        if (ls == 0) wrB(bB);
        __syncthreads();
    }
    // Y[lc][b*64+h][m2] write (next layer's split-K partial, ch == lc)
    f16* yp = Y + ((size_t)lc * 2048 + (size_t)b * HH) * 128;
#pragma unroll
    for (int i = 0; i < 2; ++i)
#pragma unroll
        for (int j = 0; j < 2; ++j)
#pragma unroll
            for (int r = 0; r < 4; ++r)
                yp[(size_t)(ow + i * 16 + fq * 4 + r) * 128 + n0 + j * 16 + fm] =
                    (f16)Yac[i][j][r];
}

// ---------------------------------------------------------------------------
// Final layer (i=3) + projection, only l = L-1. grid 32 (b), block 128.
// All operands LDS-staged with +1-padded pitches (conflict-free broadcasts).
// ---------------------------------------------------------------------------
__global__ __launch_bounds__(128) void k_final(const f16* __restrict__ Ofh,
                                               const f16* __restrict__ XT3,
                                               const f16* __restrict__ Ttr,
                                               const float* __restrict__ wsk,
                                               const float* __restrict__ bsk,
                                               const float* __restrict__ wp1,
                                               const float* __restrict__ bp1,
                                               const float* __restrict__ wp2,
                                               const float* __restrict__ bp2,
                                               float* __restrict__ out) {
    __shared__ float ofs[64 * 129];    // Of[b] fp32, pitch 129
    __shared__ float wsks[64 * 65];    // w_skip[3], pitch 65
    __shared__ float wp1s[128 * 65];   // w_p1, pitch 65
    __shared__ float tl[128], xl[64], x4[64], y[128];
    const int b = blockIdx.x, t = threadIdx.x;
    {   // Of[b]: 8192 f16 coalesced
#pragma unroll
        for (int i = 0; i < 8; ++i) {
            int g = t + i * 128;
            f16x8 v = *(const f16x8*)(Ofh + (size_t)b * HH * 128 + g * 8);
            int o = g >> 4, k0 = (g & 15) * 8;
#pragma unroll
            for (int e = 0; e < 8; ++e) ofs[o * 129 + k0 + e] = (float)v[e];
        }
    }
    {   // wsk[3]: 4096 f32
        const float* src = wsk + 3 * HH * HH;
#pragma unroll
        for (int i = 0; i < 8; ++i) {
            int g = t + i * 128;
            float4 v = CF4(src + g * 4);
            int o = g >> 4, c0 = (g & 15) * 4;
            F4(&wsks[o * 65 + c0]) = v;
        }
    }
    {   // wp1: 8192 f32
#pragma unroll
        for (int i = 0; i < 16; ++i) {
            int g = t + i * 128;
            float4 v = CF4(wp1 + g * 4);
            int p = g >> 4, c0 = (g & 15) * 4;
            F4(&wp1s[p * 65 + c0]) = v;
        }
    }
    tl[t] = (float)Ttr[(size_t)(LL - 1) * 128 + t];
    if (t < 64) xl[t] = (float)XT3[((size_t)b * LL + (LL - 1)) * HH + t];
    __syncthreads();
    if (t < 64) {
        const int o = t;
        float acc = bsk[3 * HH + o];
        for (int k = 0; k < 128; ++k) acc += ofs[o * 129 + k] * tl[k];
        for (int i = 0; i < 64; ++i) acc += wsks[o * 65 + i] * xl[i];
        x4[o] = acc;   // no gelu after last FNO layer
    }
    __syncthreads();
    {
        float acc = bp1[t];
        for (int h = 0; h < 64; ++h) acc += wp1s[t * 65 + h] * x4[h];
        y[t] = gelu_fast(acc);
    }
    __syncthreads();
    if (t < 8) {
        float acc = bp2[t];
        for (int p = 0; p < 128; ++p) acc += wp2[t * 128 + p] * y[p];
        out[b * 8 + t] = acc;   // float32 output
    }
}

// ---------------------------------------------------------------------------
extern "C" void kernel_launch(void* const* d_in, const int* in_sizes, int n_in,
                              void* d_out, int out_size, void* d_ws, size_t ws_size,
                              hipStream_t stream) {
    (void)in_sizes; (void)n_in; (void)out_size; (void)ws_size;
    const float* u   = (const float*)d_in[0];
    const float* z   = (const float*)d_in[1];
    // d_in[2] = t, unused by the reference
    const float* wl  = (const float*)d_in[3];
    const float* bl  = (const float*)d_in[4];
    const float* swr = (const float*)d_in[5];
    const float* swi = (const float*)d_in[6];
    const float* wsk = (const float*)d_in[7];
    const float* bsk = (const float*)d_in[8];
    const float* wp1 = (const float*)d_in[9];
    const float* bp1 = (const float*)d_in[10];
    const float* wp2 = (const float*)d_in[11];
    const float* bp2 = (const float*)d_in[12];
    float* out = (float*)d_out;

    f16* ws    = (f16*)d_ws;
    f16* XTa   = ws;                  // 8,388,608 h (16 MB)  [b][l][h]
    f16* XTb   = XTa + 8388608;       // 8,388,608 h
    f16* Tdt   = XTb + 8388608;       //   524,288 h  [m2][l]
    f16* Ttr   = Tdt + 524288;        //   524,288 h  [l][m2]
    f16* Ofh   = Ttr + 524288;        //   262,144 h  [b][o][m2]
    f16* wskh  = Ofh + 262144;        //    16,384 h
    f16* wrh   = wskh + 16384;        // 1,048,576 h
    f16* wih   = wrh + 1048576;       // 1,048,576 h
    f16* Yb    = wih + 1048576;       // 4,194,304 h  (8 MB, 16-chunk split-K)
    // total ~49 MB

    k_init<<<2560, 256, 0, stream>>>(u, z, wl, bl, wsk, swr, swi,
                                     Tdt, Ttr, wskh, wrh, wih, XTa);

    // layer-0 DFT (x0 came from global); layers 1..3 DFTs are fused into recon
    k_dft<<<dim3(32, 32), 256, 0, stream>>>(XTa, Tdt, Yb);

    f16* xtc = XTa; f16* xtn = XTb;
    for (int layer = 0; layer < 4; ++layer) {
        k_spec<<<dim3(32, 16), 256, 0, stream>>>(Yb, wrh, wih, Ofh, layer);
        if (layer < 3) {
            k_fused<<<dim3(16, 32), 512, 0, stream>>>(Ofh, xtc, Ttr, wskh, bsk,
                                                      Tdt, xtn, Yb, layer);
            f16* tmp = xtc; xtc = xtn; xtn = tmp;
        } else {
            k_final<<<32, 128, 0, stream>>>(Ofh, xtc, Ttr, wsk, bsk,
                                            wp1, bp1, wp2, bp2, out);
        }
    }
}

// Round 12
// 192.855 us; speedup vs baseline: 1.1170x; 1.1170x over previous
//
#include <hip/hip_runtime.h>
#include <math.h>

typedef _Float16 f16;
typedef f16  f16x2 __attribute__((ext_vector_type(2)));
typedef f16  f16x4 __attribute__((ext_vector_type(4)));
typedef f16  f16x8 __attribute__((ext_vector_type(8)));
typedef float f32x4 __attribute__((ext_vector_type(4)));

#define F4(p)  (*(float4*)(p))
#define CF4(p) (*(const float4*)(p))

namespace {
constexpr int LL = 4096;   // sequence
constexpr int HH = 64;     // channels
constexpr int NCH = 16;    // split-K l-chunks (256 l each)

__device__ __forceinline__ float gelu_fast(float x) {
    // 0.5x(1+tanh(i)) == x*sigmoid(2i); exp-neg form is NaN-free at +/-inf
    float inner = 0.7978845608028654f * (x + 0.044715f * x * x * x);
    float e = __expf(-2.0f * inner);
    return x / (1.0f + e);
}

__device__ __forceinline__ f32x4 mfma16(f16x8 a, f16x8 b, f32x4 c) {
    return __builtin_amdgcn_mfma_f32_16x16x32_f16(a, b, c, 0, 0, 0);
}
} // namespace

// ---------------------------------------------------------------------------
// k_init: fused lift [0,512) + twiddle [512,1536) + wr/wi fp16 cvt [1536,2560)
//   Tdt[m2][l]:  cos(2pi m l/L), -sin                (DFT weights, f16)
//   Ttr[l][m2]: (m==0?1:2cos)/L, (m==0?0:-2sin)/L    (irfft weights, f16)
// Both tables written COALESCED (lane runs along the contiguous dim).
// ---------------------------------------------------------------------------
__global__ __launch_bounds__(256) void k_init(const float* __restrict__ u,
                                              const float* __restrict__ z,
                                              const float* __restrict__ wl,
                                              const float* __restrict__ bl,
                                              const float* __restrict__ wsk,
                                              const float* __restrict__ wr,
                                              const float* __restrict__ wi,
                                              f16* __restrict__ Tdt,
                                              f16* __restrict__ Ttr,
                                              f16* __restrict__ wskh,
                                              f16* __restrict__ wrh,
                                              f16* __restrict__ wih,
                                              f16* __restrict__ XT0) {
    const int bid = blockIdx.x;
    const int t = threadIdx.x;
    if (bid < 512) {
        // ---- lift: XT0[b][l][h], register-tiled 8h x 8l per thread
        const int b = bid >> 4;
        const int l0 = (bid & 15) * 256;
        constexpr int IP = 260;
        __shared__ float in_s[16 * IP];
        __shared__ float wsh[64 * 16];
        __shared__ float bsh[64];
        for (int i = t; i < 1024; i += 256) wsh[i] = wl[i];
        if (t < 64) bsh[t] = bl[t];
#pragma unroll
        for (int q = 0; q < 2; ++q) {
            int f = t + q * 256;
            int l = f >> 1, cq = (f & 1) * 4;
            float4 v = CF4(u + ((size_t)b * LL + l0 + l) * 8 + cq);
            in_s[(cq + 0) * IP + l] = v.x;
            in_s[(cq + 1) * IP + l] = v.y;
            in_s[(cq + 2) * IP + l] = v.z;
            in_s[(cq + 3) * IP + l] = v.w;
        }
        for (int f = t; f < 8 * 256; f += 256) {
            int c = f >> 8, l = f & 255;
            in_s[(8 + c) * IP + l] = z[b * 8 + c];
        }
        __syncthreads();
        const int hg = t >> 5, lsub = t & 31;
        float acc[8][8] = {};
        for (int c = 0; c < 16; ++c) {
            float wv[8], inv[8];
#pragma unroll
            for (int i = 0; i < 8; ++i) wv[i] = wsh[(hg * 8 + i) * 16 + c];
#pragma unroll
            for (int j = 0; j < 8; ++j) inv[j] = in_s[c * IP + lsub + 32 * j];
#pragma unroll
            for (int i = 0; i < 8; ++i)
#pragma unroll
                for (int j = 0; j < 8; ++j) acc[i][j] += wv[i] * inv[j];
        }
#pragma unroll
        for (int j = 0; j < 8; ++j) {
            __attribute__((aligned(16))) f16 hv[8];
#pragma unroll
            for (int i = 0; i < 8; ++i) hv[i] = (f16)(acc[i][j] + bsh[hg * 8 + i]);
            int l = l0 + lsub + 32 * j;
            F4(XT0 + ((size_t)b * LL + l) * HH + hg * 8) = CF4(hv);
        }
    } else if (bid < 1536) {
        // ---- twiddle (both orientations coalesced)
        const int tb = bid - 512;
        const float w0 = 6.283185307179586f / 4096.0f;
        {   // Tdt: lane runs along l
            int m = tb >> 4;
            int l = ((tb & 15) << 8) + t;
            float s, c;
            sincosf((float)((l * m) & 4095) * w0, &s, &c);
            Tdt[(size_t)(2 * m) * LL + l]     = (f16)c;
            Tdt[(size_t)(2 * m + 1) * LL + l] = (f16)(-s);
        }
        {   // Ttr: lane runs along m2 (4B per lane)
            int l = tb * 4 + (t >> 6);
            int m = t & 63;
            float s, c;
            sincosf((float)((l * m) & 4095) * w0, &s, &c);
            const float sc = 1.0f / 4096.0f;
            f16x2 pv;
            pv.x = (f16)((m == 0) ? sc : 2.0f * sc * c);
            pv.y = (f16)((m == 0) ? 0.0f : -2.0f * sc * s);
            *(f16x2*)(Ttr + (size_t)l * 128 + 2 * m) = pv;
        }
        if (tb < 64) {
            int idx = tb * 256 + t;
            wskh[idx] = (f16)wsk[idx];
        }
    } else {
        // ---- wr/wi -> f16 (4 elements each per thread)
        const int cb = bid - 1536;
        size_t base = (size_t)cb * 1024 + t * 4;
        float4 vr = CF4(wr + base);
        float4 vi = CF4(wi + base);
        f16x4 hr, hi;
        hr.x = (f16)vr.x; hr.y = (f16)vr.y; hr.z = (f16)vr.z; hr.w = (f16)vr.w;
        hi.x = (f16)vi.x; hi.y = (f16)vi.y; hi.z = (f16)vi.z; hi.w = (f16)vi.w;
        *(f16x4*)(wrh + base) = hr;
        *(f16x4*)(wih + base) = hi;
    }
}

// ---------------------------------------------------------------------------
// Partial DFT (LAYER 0 ONLY), fp16 MFMA, 16-chunk split (K=256 each):
//   Y[ch][(b,h)][m2] = sum_{l in 256-chunk} XT[b][l][h] * Tdt[m2][l]   (f16 out)
// grid (32 = ch*2+hhalf, 32 b), block 256 (4 waves). Tile 32 h x 128 m2.
// (r9-verbatim: register-prefetch rejected twice — r4, r10.)
// ---------------------------------------------------------------------------
__global__ __launch_bounds__(256) void k_dft(const f16* __restrict__ XT,
                                             const f16* __restrict__ Tdt,
                                             f16* __restrict__ Y) {
    __shared__ f16 Asl[32 * 72];    // [h][l-chunk] pitch 72
    __shared__ f16 Bsl[128 * 72];   // [m2][l-chunk] pitch 72
    const int t = threadIdx.x;
    const int ch = blockIdx.x >> 1, h0 = (blockIdx.x & 1) * 32, b = blockIdx.y;
    const int lane = t & 63, wid = t >> 6;
    const int mh = (wid & 1) * 16, n0 = (wid >> 1) * 64;
    const int fm = lane & 15, fq = lane >> 4;
    f32x4 acc[4] = {};
    for (int k0 = 0; k0 < 256; k0 += 64) {
        const int l0 = ch * 256 + k0;
        __syncthreads();
        {   // A: XT[b][l][h0..h0+32] -> Asl[h][l] (LDS transpose, 2-way free)
            int seg = t >> 6;   // 4 segs x 8 h
            f16x8 v = *(const f16x8*)(XT + ((size_t)b * LL + l0 + lane) * HH + h0 + seg * 8);
#pragma unroll
            for (int i = 0; i < 8; ++i) Asl[(seg * 8 + i) * 72 + lane] = v[i];
        }
#pragma unroll
        for (int p = 0; p < 4; ++p) {   // B: Tdt[m2][l0..l0+63]
            int r = (t >> 3) + p * 32;
            F4(&Bsl[r * 72 + (t & 7) * 8]) = CF4(Tdt + (size_t)r * LL + l0 + (t & 7) * 8);
        }
        __syncthreads();
#pragma unroll
        for (int ks = 0; ks < 64; ks += 32) {
            f16x8 a = *(const f16x8*)&Asl[(mh + fm) * 72 + ks + fq * 8];
#pragma unroll
            for (int j = 0; j < 4; ++j) {
                f16x8 bj = *(const f16x8*)&Bsl[(n0 + j * 16 + fm) * 72 + ks + fq * 8];
                acc[j] = mfma16(a, bj, acc[j]);
            }
        }
    }
    f16* yp = Y + ((size_t)ch * 2048 + b * HH + h0) * 128;
#pragma unroll
    for (int j = 0; j < 4; ++j)
#pragma unroll
        for (int r = 0; r < 4; ++r)
            yp[(size_t)(mh + fq * 4 + r) * 128 + n0 + j * 16 + fm] = (f16)acc[j][r];
}

// ---------------------------------------------------------------------------
// Spectral mix + split-K reduce (16 chunks). grid (32 b, 8 og), block 512:
// halves the redundant Y re-staging (8 blocks/b instead of 16) while keeping
// 8 waves/CU (r5's 4-wave trap avoided). Per-thread math/order identical.
// ---------------------------------------------------------------------------
__global__ __launch_bounds__(512) void k_spec(const f16* __restrict__ Y,
                                              const f16* __restrict__ wrh,
                                              const f16* __restrict__ wih,
                                              f16* __restrict__ Ofh, int layer) {
    __shared__ float xsh[64 * 128];
    const int t = threadIdx.x;
    const int b = blockIdx.x;
    const int og = blockIdx.y;
    {   // stage Xf[b] = sum_ch Y[ch][b]  (ascending ch, fp32 accum)
#pragma unroll
        for (int i = 0; i < 2; ++i) {
            int g = t + i * 512;            // f16x8 group, 1024 total
            float s[8] = {};
#pragma unroll
            for (int c = 0; c < NCH; ++c) {
                f16x8 v = *(const f16x8*)(Y + ((size_t)c * 2048 + b * HH) * 128 + g * 8);
#pragma unroll
                for (int e = 0; e < 8; ++e) s[e] += (float)v[e];
            }
#pragma unroll
            for (int e = 0; e < 8; ++e) xsh[g * 8 + e] = s[e];
        }
    }
    __syncthreads();
    const int m = t & 63, osub = t >> 6;    // osub 0..7
    const int o = og * 8 + osub;
    const f16* wrp = wrh + ((size_t)layer * HH + o) * HH * 64 + m;
    const f16* wip = wih + ((size_t)layer * HH + o) * HH * 64 + m;
    float are = 0.0f, aim = 0.0f;
    const float2* xs2 = (const float2*)xsh;
#pragma unroll 8
    for (int i = 0; i < 64; ++i) {
        float2 xv = xs2[i * 64 + m];
        float wrv = (float)wrp[(size_t)i * 64];
        float wiv = (float)wip[(size_t)i * 64];
        are += xv.x * wrv - xv.y * wiv;
        aim += xv.x * wiv + xv.y * wrv;
    }
    f16x2 ov; ov.x = (f16)are; ov.y = (f16)aim;
    *(f16x2*)(Ofh + ((size_t)b * HH + o) * 128 + 2 * m) = ov;
}

// ---------------------------------------------------------------------------
// FUSED recon(layer) + partial-DFT(layer+1), layers 0..2.
// grid (16 lc, 32 b) = 512 blocks, block 512 (8 waves), 2 blocks/CU.
// DOUBLE-BUFFERED Bsl (B0/B1, 80.1 KB total): each phase issues next chunk's
// global loads, runs MFMA on buf[p], then ds_writes buf[p^1] — the barrier's
// vmcnt(0) drain lands AFTER a full MFMA cluster instead of immediately after
// issue. (r9-verbatim — validated +3 µs win.)
// ---------------------------------------------------------------------------
__global__ __launch_bounds__(512, 4) void k_fused(const f16* __restrict__ Ofh,
                                                  const f16* __restrict__ XTold,
                                                  const f16* __restrict__ Ttr,
                                                  const f16* __restrict__ wskh,
                                                  const float* __restrict__ bsk,
                                                  const f16* __restrict__ Tdt,
                                                  f16* __restrict__ XTn,
                                                  f16* __restrict__ Y,
                                                  int layer) {
    __shared__ __align__(16) char smem[80128];
    f16* Asl = (f16*)smem;                 // [64][200] = 25600
    f16* XA  = (f16*)(smem + 25600);       // [64][136] = 17408 (ends 43008)
    f16* B0  = (f16*)(smem + 43008);       // [128][72] = 18432 (ends 61440)
    f16* B1  = (f16*)(smem + 61440);       // [128][72] = 18432 (ends 79872)
    float* bss = (float*)(smem + 79872);   // 64*4 = 256 (ends 80128)
    const int t = threadIdx.x;
    const int lc = blockIdx.x, b = blockIdx.y;
    const int lane = t & 63, wid = t >> 6;
    const int ow = (wid & 1) * 32;        // o rows (recon) / h rows (dft)
    const int n0 = (wid >> 1) * 32;       // l cols (recon) / m2 cols (dft)
    const int fm = lane & 15, fq = lane >> 4;
    const int br = t >> 3, bcol = (t & 7) * 8;   // B-stage rows br, br+64 @ col bcol

    float4 rB0, rB1;
    auto ldR = [&](int ls, int c) {       // recon B rows: Ttr (c<2) or XTold (c==2)
        const int l0g = lc * 256 + ls * 128;
        if (c < 2) {
            rB0 = CF4(Ttr + (size_t)(l0g + br) * 128 + c * 64 + bcol);
            rB1 = CF4(Ttr + (size_t)(l0g + br + 64) * 128 + c * 64 + bcol);
        } else {
            rB0 = CF4(XTold + ((size_t)b * LL + l0g + br) * HH + bcol);
            rB1 = CF4(XTold + ((size_t)b * LL + l0g + br + 64) * HH + bcol);
        }
    };
    auto ldD = [&](int ls, int c) {       // dft B rows: Tdt[m2][l-chunk]
        const int l0 = lc * 256 + ls * 128 + c * 64;
        rB0 = CF4(Tdt + (size_t)br * LL + l0 + bcol);
        rB1 = CF4(Tdt + (size_t)(br + 64) * LL + l0 + bcol);
    };
    auto wrB = [&](f16* buf) {
        F4(&buf[br * 72 + bcol]) = rB0;
        F4(&buf[(br + 64) * 72 + bcol]) = rB1;
    };
    f32x4 acc[2][2];
    f32x4 Yac[2][2] = {};
    auto reconMM = [&](const f16* buf, int k0) {
#pragma unroll
        for (int ks = 0; ks < 64; ks += 32) {
            f16x8 a0 = *(const f16x8*)&Asl[(ow + fm) * 200 + k0 + ks + fq * 8];
            f16x8 a1 = *(const f16x8*)&Asl[(ow + 16 + fm) * 200 + k0 + ks + fq * 8];
#pragma unroll
            for (int j = 0; j < 2; ++j) {
                f16x8 bj = *(const f16x8*)&buf[(n0 + j * 16 + fm) * 72 + ks + fq * 8];
                acc[0][j] = mfma16(a0, bj, acc[0][j]);
                acc[1][j] = mfma16(a1, bj, acc[1][j]);
            }
        }
    };
    auto dftMM = [&](const f16* buf, int c) {
#pragma unroll
        for (int ks = 0; ks < 64; ks += 32) {
            f16x8 a0 = *(const f16x8*)&XA[(ow + fm) * 136 + c * 64 + ks + fq * 8];
            f16x8 a1 = *(const f16x8*)&XA[(ow + 16 + fm) * 136 + c * 64 + ks + fq * 8];
#pragma unroll
            for (int j = 0; j < 2; ++j) {
                f16x8 bj = *(const f16x8*)&buf[(n0 + j * 16 + fm) * 72 + ks + fq * 8];
                Yac[0][j] = mfma16(a0, bj, Yac[0][j]);
                Yac[1][j] = mfma16(a1, bj, Yac[1][j]);
            }
        }
    };

    {   // prologue: stage Asl = [Of[b] | wskh[layer]], bss, and R0(ls=0) -> B0
        int seg = t & 15, row = t >> 4;   // row 0..31
#pragma unroll
        for (int p = 0; p < 2; ++p) {
            int r = row + p * 32;
            F4(&Asl[r * 200 + seg * 8]) = CF4(Ofh + ((size_t)(b * HH + r)) * 128 + seg * 8);
        }
        F4(&Asl[br * 200 + 128 + bcol]) =
            CF4(wskh + ((size_t)(layer * HH + br)) * HH + bcol);
        if (t < 64) bss[t] = bsk[layer * HH + t];
        ldR(0, 0);
        wrB(B0);
    }
    __syncthreads();

#pragma unroll
    for (int ls = 0; ls < 2; ++ls) {
        const int l0g = lc * 256 + ls * 128;
        f16* bA = (ls == 0) ? B0 : B1;    // buffer holding this ls's R0
        f16* bB = (ls == 0) ? B1 : B0;
#pragma unroll
        for (int i = 0; i < 2; ++i)
#pragma unroll
            for (int j = 0; j < 2; ++j) acc[i][j] = (f32x4){0.f, 0.f, 0.f, 0.f};
        // P0: R0 MFMA on bA; prefetch R1 -> bB
        ldR(ls, 1);
        reconMM(bA, 0);
        wrB(bB);
        __syncthreads();
        // P1: R1 MFMA on bB; prefetch R2 -> bA
        ldR(ls, 2);
        reconMM(bB, 64);
        wrB(bA);
        __syncthreads();
        // P2: R2 MFMA on bA; prefetch D0 -> bB
        ldD(ls, 0);
        reconMM(bA, 128);
        wrB(bB);
        __syncthreads();
        // P3: epilogue — bias+gelu; write XA[o][l] (dft A) + bA[l][o] (XT stage)
#pragma unroll
        for (int i = 0; i < 2; ++i)
#pragma unroll
            for (int r = 0; r < 4; ++r) {
                int row = ow + i * 16 + fq * 4 + r;
                float bias = bss[row];
#pragma unroll
                for (int j = 0; j < 2; ++j) {
                    int lcn = n0 + j * 16 + fm;
                    f16 hv = (f16)gelu_fast(acc[i][j][r] + bias);
                    XA[row * 136 + lcn] = hv;
                    bA[lcn * 72 + row] = hv;
                }
            }
        __syncthreads();
        // P4: XTn write from bA ∥ D0 MFMA on bB ∥ issue D1 loads
        if (layer < 2) {
            F4(XTn + ((size_t)b * LL + l0g + br) * HH + bcol) = CF4(&bA[br * 72 + bcol]);
            F4(XTn + ((size_t)b * LL + l0g + br + 64) * HH + bcol) =
                CF4(&bA[(br + 64) * 72 + bcol]);
        } else if (lc == NCH - 1 && ls == 1) {
            // layer 2: only l = L-1 is ever consumed (k_final skip term)
            if (t < 64) XTn[((size_t)b * LL + (LL - 1)) * HH + t] = bA[127 * 72 + t];
        }
        ldD(ls, 1);
        dftMM(bB, 0);
        __syncthreads();
        // P5: D1 -> bA (XTn-stage reads done); prefetch next ls's R0
        wrB(bA);
        if (ls == 0) ldR(1, 0);
        __syncthreads();
        // P6: D1 MFMA on bA; stage next R0 -> bB
        dftMM(bA, 1);
        if (ls == 0) wrB(bB);
        __syncthreads();
    }
    // Y[lc][b*64+h][m2] write (next layer's split-K partial, ch == lc)
    f16* yp = Y + ((size_t)lc * 2048 + (size_t)b * HH) * 128;
#pragma unroll
    for (int i = 0; i < 2; ++i)
#pragma unroll
        for (int j = 0; j < 2; ++j)
#pragma unroll
            for (int r = 0; r < 4; ++r)
                yp[(size_t)(ow + i * 16 + fq * 4 + r) * 128 + n0 + j * 16 + fm] =
                    (f16)Yac[i][j][r];
}

// ---------------------------------------------------------------------------
// Final layer (i=3) + projection, only l = L-1. grid 32 (b), block 128.
// All operands LDS-staged with +1-padded pitches (conflict-free broadcasts).
// ---------------------------------------------------------------------------
__global__ __launch_bounds__(128) void k_final(const f16* __restrict__ Ofh,
                                               const f16* __restrict__ XT3,
                                               const f16* __restrict__ Ttr,
                                               const float* __restrict__ wsk,
                                               const float* __restrict__ bsk,
                                               const float* __restrict__ wp1,
                                               const float* __restrict__ bp1,
                                               const float* __restrict__ wp2,
                                               const float* __restrict__ bp2,
                                               float* __restrict__ out) {
    __shared__ float ofs[64 * 129];    // Of[b] fp32, pitch 129
    __shared__ float wsks[64 * 65];    // w_skip[3], pitch 65
    __shared__ float wp1s[128 * 65];   // w_p1, pitch 65
    __shared__ float tl[128], xl[64], x4[64], y[128];
    const int b = blockIdx.x, t = threadIdx.x;
    {   // Of[b]: 8192 f16 coalesced
#pragma unroll
        for (int i = 0; i < 8; ++i) {
            int g = t + i * 128;
            f16x8 v = *(const f16x8*)(Ofh + (size_t)b * HH * 128 + g * 8);
            int o = g >> 4, k0 = (g & 15) * 8;
#pragma unroll
            for (int e = 0; e < 8; ++e) ofs[o * 129 + k0 + e] = (float)v[e];
        }
    }
    {   // wsk[3]: 4096 f32
        const float* src = wsk + 3 * HH * HH;
#pragma unroll
        for (int i = 0; i < 8; ++i) {
            int g = t + i * 128;
            float4 v = CF4(src + g * 4);
            int o = g >> 4, c0 = (g & 15) * 4;
            F4(&wsks[o * 65 + c0]) = v;
        }
    }
    {   // wp1: 8192 f32
#pragma unroll
        for (int i = 0; i < 16; ++i) {
            int g = t + i * 128;
            float4 v = CF4(wp1 + g * 4);
            int p = g >> 4, c0 = (g & 15) * 4;
            F4(&wp1s[p * 65 + c0]) = v;
        }
    }
    tl[t] = (float)Ttr[(size_t)(LL - 1) * 128 + t];
    if (t < 64) xl[t] = (float)XT3[((size_t)b * LL + (LL - 1)) * HH + t];
    __syncthreads();
    if (t < 64) {
        const int o = t;
        float acc = bsk[3 * HH + o];
        for (int k = 0; k < 128; ++k) acc += ofs[o * 129 + k] * tl[k];
        for (int i = 0; i < 64; ++i) acc += wsks[o * 65 + i] * xl[i];
        x4[o] = acc;   // no gelu after last FNO layer
    }
    __syncthreads();
    {
        float acc = bp1[t];
        for (int h = 0; h < 64; ++h) acc += wp1s[t * 65 + h] * x4[h];
        y[t] = gelu_fast(acc);
    }
    __syncthreads();
    if (t < 8) {
        float acc = bp2[t];
        for (int p = 0; p < 128; ++p) acc += wp2[t * 128 + p] * y[p];
        out[b * 8 + t] = acc;   // float32 output
    }
}

// ---------------------------------------------------------------------------
extern "C" void kernel_launch(void* const* d_in, const int* in_sizes, int n_in,
                              void* d_out, int out_size, void* d_ws, size_t ws_size,
                              hipStream_t stream) {
    (void)in_sizes; (void)n_in; (void)out_size; (void)ws_size;
    const float* u   = (const float*)d_in[0];
    const float* z   = (const float*)d_in[1];
    // d_in[2] = t, unused by the reference
    const float* wl  = (const float*)d_in[3];
    const float* bl  = (const float*)d_in[4];
    const float* swr = (const float*)d_in[5];
    const float* swi = (const float*)d_in[6];
    const float* wsk = (const float*)d_in[7];
    const float* bsk = (const float*)d_in[8];
    const float* wp1 = (const float*)d_in[9];
    const float* bp1 = (const float*)d_in[10];
    const float* wp2 = (const float*)d_in[11];
    const float* bp2 = (const float*)d_in[12];
    float* out = (float*)d_out;

    f16* ws    = (f16*)d_ws;
    f16* XTa   = ws;                  // 8,388,608 h (16 MB)  [b][l][h]
    f16* XTb   = XTa + 8388608;       // 8,388,608 h
    f16* Tdt   = XTb + 8388608;       //   524,288 h  [m2][l]
    f16* Ttr   = Tdt + 524288;        //   524,288 h  [l][m2]
    f16* Ofh   = Ttr + 524288;        //   262,144 h  [b][o][m2]
    f16* wskh  = Ofh + 262144;        //    16,384 h
    f16* wrh   = wskh + 16384;        // 1,048,576 h
    f16* wih   = wrh + 1048576;       // 1,048,576 h
    f16* Yb    = wih + 1048576;       // 4,194,304 h  (8 MB, 16-chunk split-K)
    // total ~49 MB

    k_init<<<2560, 256, 0, stream>>>(u, z, wl, bl, wsk, swr, swi,
                                     Tdt, Ttr, wskh, wrh, wih, XTa);

    // layer-0 DFT (x0 came from global); layers 1..3 DFTs are fused into recon
    k_dft<<<dim3(32, 32), 256, 0, stream>>>(XTa, Tdt, Yb);

    f16* xtc = XTa; f16* xtn = XTb;
    for (int layer = 0; layer < 4; ++layer) {
        k_spec<<<dim3(32, 8), 512, 0, stream>>>(Yb, wrh, wih, Ofh, layer);
        if (layer < 3) {
            k_fused<<<dim3(16, 32), 512, 0, stream>>>(Ofh, xtc, Ttr, wskh, bsk,
                                                      Tdt, xtn, Yb, layer);
            f16* tmp = xtc; xtc = xtn; xtn = tmp;
        } else {
            k_final<<<32, 128, 0, stream>>>(Ofh, xtc, Ttr, wsk, bsk,
                                            wp1, bp1, wp2, bp2, out);
        }
    }
}